// Round 9
// baseline (255.740 us; speedup 1.0000x reference)
//
#include <hip/hip_runtime.h>
#include <hip/hip_bf16.h>

// GAT layer: out = h = x @ W^T  (N=200000 x 128, fp32 in / fp32 out), then
// E=500 edges: out[dst] += 0.1 * leaky_relu(attn, 0.2) * h[src].
//
// K1 evidence trail (all clean-traffic configs pinned at 2.05-2.46 TB/s):
//   R0 scattered, 782blk (3.05/CU, grid-limited):  2.07
//   R2 scattered+prefetch, 512blk (2/CU):          2.05
//   R5 contig+convoy, 768blk (3/CU LDS-capped):    2.43
//   R6 contig barrier-free:                        2.33
//   R7 +coalesced stores:                          2.43 (traffic exactly clean)
//   R8 +2-deep ping-pong:                          2.31
//   references: fill 6.4 TB/s, m13 copy 6.3, RMSNorm 4.9 -- all are
//   tiny-VGPR streaming kernels at ~32 waves/CU.
// Load shape, store shape, depth, barriers: each isolated, none moved BW
// >20%. The never-isolated axis: RESIDENT WAVES (never above ~12/CU;
// BW/wave ~constant 1.1-1.5 GB/s across all variants). R9 removes every
// occupancy cap: LDS = Ws only (34816 B -> 4 blocks/CU), launch_bounds
// (256,4) (VGPR<=128; R2 measured 112), grid 1024 -> 16 waves/CU, direct
// frag loads + 1-deep prefetch (R2 pattern, clean), direct D-layout
// stores, bijective XCD swizzle for L2-local sweeps.
// K2/K3 unchanged (race-free two-phase edge update).

typedef __attribute__((ext_vector_type(8))) short bf16x8;   // 8 bf16 = 4 VGPRs
typedef __attribute__((ext_vector_type(4))) float f32x4;

#define W_PAD 136   // 128 + 8 bf16; 272 B stride: frag-read conflicts benign;
                    // do NOT drop to 128 (16-way conflict: bank = f(q) only)

__device__ __forceinline__ bf16x8 pack_bf16x8(float4 v0, float4 v1) {
  union { bf16x8 v; __hip_bfloat16 h[8]; } u;
  u.h[0] = __float2bfloat16(v0.x); u.h[1] = __float2bfloat16(v0.y);
  u.h[2] = __float2bfloat16(v0.z); u.h[3] = __float2bfloat16(v0.w);
  u.h[4] = __float2bfloat16(v1.x); u.h[5] = __float2bfloat16(v1.y);
  u.h[6] = __float2bfloat16(v1.z); u.h[7] = __float2bfloat16(v1.w);
  return u.v;
}

__global__ __launch_bounds__(256, 4) void gat_gemm_kernel(
    const float* __restrict__ x,
    const float* __restrict__ W,
    float* __restrict__ out,
    int N) {
  __shared__ __hip_bfloat16 Ws[128 * W_PAD];   // 34816 B -> 4 blocks/CU

  const int tid = threadIdx.x;

  // Stage W (128x128 fp32 = 64 KB) into LDS as bf16. One-time per block.
  #pragma unroll
  for (int it = 0; it < 16; ++it) {
    int seg = tid + it * 256;          // 0..4095 float4 segments
    int row = seg >> 5;                // 32 segments per 128-col row
    int off = (seg & 31) * 4;
    float4 v = *reinterpret_cast<const float4*>(&W[row * 128 + off]);
    union { ushort4 u4; __hip_bfloat16 h[4]; } wpk;
    wpk.h[0] = __float2bfloat16(v.x);
    wpk.h[1] = __float2bfloat16(v.y);
    wpk.h[2] = __float2bfloat16(v.z);
    wpk.h[3] = __float2bfloat16(v.w);
    *reinterpret_cast<ushort4*>(&Ws[row * W_PAD + off]) = wpk.u4;
  }
  __syncthreads();   // one-time; no barriers after this point

  const int wave = tid >> 6;
  const int lane = tid & 63;
  const int m = lane & 15;     // W row (= out col) in A-frag / x row in B-frag
  const int q = lane >> 4;     // quad: k-subchunk q*8, D reg row q*4+j

  // Bijective XCD swizzle (gridDim.x % 8 == 0): XCD gets contiguous range.
  const int nwg = (int)gridDim.x;
  const int bid = (int)blockIdx.x;
  const int swz = (bid & 7) * (nwg >> 3) + (bid >> 3);

  const int tiles = N >> 4;              // 16-row tiles: 12500
  const int gw = nwg * 4;                // total waves = tile stride (4096)
  int t = swz * 4 + wave;
  if (t >= tiles) return;                // wave-uniform; no barriers below

  // Prefetch x frags for tile t: lane(m,q) holds x[t*16+m][s*32+q*8 .. +7].
  float4 raw[8];
  {
    const float* xrow = x + (long)(t * 16 + m) * 128;
    #pragma unroll
    for (int s = 0; s < 4; ++s) {
      raw[2 * s]     = *reinterpret_cast<const float4*>(xrow + s * 32 + q * 8);
      raw[2 * s + 1] = *reinterpret_cast<const float4*>(xrow + s * 32 + q * 8 + 4);
    }
  }

  while (true) {
    // Convert current tile's x to bf16 B-fragments (frees raw for refill).
    bf16x8 af[4];
    #pragma unroll
    for (int s = 0; s < 4; ++s) af[s] = pack_bf16x8(raw[2 * s], raw[2 * s + 1]);

    // Issue next tile's loads now -> in flight across MFMA + store.
    const int tn = t + gw;
    if (tn < tiles) {
      const float* xrow = x + (long)(tn * 16 + m) * 128;
      #pragma unroll
      for (int s = 0; s < 4; ++s) {
        raw[2 * s]     = *reinterpret_cast<const float4*>(xrow + s * 32 + q * 8);
        raw[2 * s + 1] = *reinterpret_cast<const float4*>(xrow + s * 32 + q * 8 + 4);
      }
    }

    // D[r][c] = sum_k W[nt*16+r][k] * x[t*16+c][k] (A=W from LDS, B=x).
    f32x4 acc[8];
    #pragma unroll
    for (int nt = 0; nt < 8; ++nt) acc[nt] = (f32x4){0.f, 0.f, 0.f, 0.f};
    #pragma unroll
    for (int s = 0; s < 4; ++s) {
      #pragma unroll
      for (int nt = 0; nt < 8; ++nt) {
        bf16x8 wfrag = *reinterpret_cast<const bf16x8*>(
            &Ws[(nt * 16 + m) * W_PAD + s * 32 + q * 8]);
        acc[nt] = __builtin_amdgcn_mfma_f32_16x16x32_bf16(wfrag, af[s],
                                                          acc[nt], 0, 0, 0);
      }
    }

    // D (reg j, lane) -> out[t*16 + m][nt*16 + q*4 + j]: f32x4 per nt.
    float* orow = out + (long)(t * 16 + m) * 128 + q * 4;
    #pragma unroll
    for (int nt = 0; nt < 8; ++nt)
      *reinterpret_cast<f32x4*>(orow + nt * 16) = acc[nt];

    if (tn >= tiles) break;
    t = tn;
  }
}

__device__ __forceinline__ int detect_i64(const int* eidx) {
  int or_odd = 0;
  #pragma unroll
  for (int k = 0; k < 16; ++k) or_odd |= eidx[2 * k + 1];
  return or_odd == 0;   // int64 little-endian: high words all zero
}

// Phase A: one block per edge. Read h rows from `out` (pure read), compute
// attn, write contribution vector 0.1*attn*h_src to ws. No races.
__global__ __launch_bounds__(128) void gat_edge_attn(
    const int* __restrict__ eidx,
    const float* __restrict__ a,       // [4, 64]
    const float* __restrict__ h,       // == out, post-GEMM
    float* __restrict__ contrib,       // [E, 128] in ws
    int E) {
  const int e = blockIdx.x;
  const int c = threadIdx.x;
  const bool is64 = detect_i64(eidx);
  const int src = is64 ? eidx[2 * e] : eidx[e];
  const int dst = is64 ? eidx[2 * (E + e)] : eidx[E + e];

  const float hs = h[(long)src * 128 + c];
  const float hd = h[(long)dst * 128 + c];

  const int head = c >> 5, d = c & 31;
  float term = a[head * 64 + d] * hs + a[head * 64 + 32 + d] * hd;
  // reduce over the 32 lanes of this head (heads occupy 32-lane halves)
  term += __shfl_xor(term, 16);
  term += __shfl_xor(term, 8);
  term += __shfl_xor(term, 4);
  term += __shfl_xor(term, 2);
  term += __shfl_xor(term, 1);
  const float attn = term >= 0.f ? term : 0.2f * term;   // leaky_relu(0.2)

  contrib[(long)e * 128 + c] = 0.1f * attn * hs;
}

// Phase B: atomic scatter-add of contributions (duplicate dst handled by HW).
__global__ __launch_bounds__(128) void gat_edge_scatter(
    const int* __restrict__ eidx,
    const float* __restrict__ contrib,
    float* __restrict__ out,
    int E) {
  const int e = blockIdx.x;
  const int c = threadIdx.x;
  const bool is64 = detect_i64(eidx);
  const int dst = is64 ? eidx[2 * (E + e)] : eidx[E + e];
  atomicAdd(&out[(long)dst * 128 + c], contrib[(long)e * 128 + c]);
}

extern "C" void kernel_launch(void* const* d_in, const int* in_sizes, int n_in,
                              void* d_out, int out_size, void* d_ws, size_t ws_size,
                              hipStream_t stream) {
  const float* x  = (const float*)d_in[0];
  const int* eidx = (const int*)d_in[1];
  const float* W  = (const float*)d_in[2];
  const float* a  = (const float*)d_in[3];
  float* out = (float*)d_out;
  float* contrib = (float*)d_ws;     // needs E*128*4 = 256 KB

  const int N = in_sizes[0] / 128;   // 200000
  const int E = in_sizes[1] / 2;     // 500

  // 1024 blocks = 4 blocks/CU (LDS allows 4, VGPR<=128 allows 4 waves/SIMD)
  // -> 16 waves/CU nominal, the first clean config above 12.
  int blocks = 1024;                 // % 8 == 0 for the XCD swizzle
  gat_gemm_kernel<<<blocks, 256, 0, stream>>>(x, W, out, N);
  gat_edge_attn<<<E, 128, 0, stream>>>(eidx, a, out, contrib, E);
  gat_edge_scatter<<<E, 128, 0, stream>>>(eidx, contrib, out, E);
}

// Round 10
// 192.339 us; speedup vs baseline: 1.3296x; 1.3296x over previous
//
#include <hip/hip_runtime.h>
#include <hip/hip_bf16.h>

// GAT layer: out = h = x @ W^T  (N=200000 x 128, fp32 in / fp32 out), then
// E=500 edges: out[dst] += 0.1 * leaky_relu(attn, 0.2) * h[src].
//
// K1 evidence matrix (10 rounds):
//   scattered x low-occ (R0/R2):   clean 154 MB @ 2.05-2.07 TB/s
//   scattered x high-occ (R3/4/9): DIRTY (FETCH 133-187, WRITE 186-335) slow
//   contiguous x low-occ (R5-R8):  clean @ 2.31-2.43 TB/s (3 blk/CU LDS cap)
//   R9 confirmed service ~ waves: 2.4 @ 12 w/CU -> 3.05 @ 16 w/CU
// R10 = the untested cell: CONTIGUOUS x HIGH-OCC. R7 structure under the
// 40 KB LDS line -> 4 blocks/CU = 16 waves/CU:
//   - Ws unpadded (32768 B) + XOR swizzle byte^=(row&7)<<4 (8 bank-groups
//     on b128 = conflict-free floor; replaces the +8 pad)
//   - ONE shared 8 KB buffer: bf16 x-stage during load/MFMA phase, f32
//     store scratch during epilogue. nt-split: wave w owns out cols
//     32w..32w+31 (acc[2]) so a single-pass 16x128 f32 scratch fits.
//   - loads 4 KB-contiguous/instr; stores 4 KB-contiguous/instr (R7 shapes)
//   - raw s_barrier + lgkmcnt(0) only (vmcnt never drained in loop),
//     1-deep prefetch, 4 barriers/tile. VGPR ~70 <= 128 (4 waves/SIMD).
// Total LDS = 32768 + 8192 = 40960 = 160K/4 exactly.
// K2/K3 unchanged (race-free two-phase edge update).

typedef __attribute__((ext_vector_type(8))) short bf16x8;   // 8 bf16 = 4 VGPRs
typedef __attribute__((ext_vector_type(4))) float f32x4;

__global__ __launch_bounds__(256, 4) void gat_gemm_kernel(
    const float* __restrict__ x,
    const float* __restrict__ W,
    float* __restrict__ out,
    int N) {
  __shared__ __align__(16) char WsB[32768];   // W as bf16, XOR-swizzled rows
  __shared__ __align__(16) char XsB[8192];    // x-stage (bf16) / store scratch (f32)

  const int tid = threadIdx.x;

  // ---- Stage W (128x128 fp32) -> WsB bf16, XOR-swizzled. One-time. ----
  #pragma unroll
  for (int it = 0; it < 16; ++it) {
    int seg = it * 256 + tid;          // 0..4095 4-float segments
    int row = seg >> 5;                // 32 segs per 128-col row
    int o8 = seg & 31;                 // 8-byte slot within row
    float4 v = *reinterpret_cast<const float4*>(&W[row * 128 + o8 * 4]);
    union { ushort4 u4; __hip_bfloat16 h[4]; } wpk;
    wpk.h[0] = __float2bfloat16(v.x);
    wpk.h[1] = __float2bfloat16(v.y);
    wpk.h[2] = __float2bfloat16(v.z);
    wpk.h[3] = __float2bfloat16(v.w);
    *reinterpret_cast<ushort4*>(
        WsB + row * 256 + ((o8 * 8) ^ ((row & 7) << 4))) = wpk.u4;
  }
  __syncthreads();   // one-time full sync

  const int wave = tid >> 6;
  const int lane = tid & 63;
  const int m = lane & 15;     // out row within tile / W-frag row index
  const int q = lane >> 4;     // quad: k-subchunk q*8, D reg row q*4+j

  const int T16 = N >> 4;                // 16-row tiles: 12500
  const int stride = (int)gridDim.x;     // 1024
  int t = (int)blockIdx.x;               // block-uniform loop

  // ---- prologue: contiguous load of tile t (2 x 4KB instrs/thread). ----
  float4 raw[2];
  {
    const float* xt = x + (long)t * 2048;     // 16*128 floats
    #pragma unroll
    for (int i = 0; i < 2; ++i)
      raw[i] = *reinterpret_cast<const float4*>(xt + (i * 256 + tid) * 4);
  }

  while (true) {
    // ---- pack raw -> XsB (bf16, XOR-swizzled rows of 256 B). ----
    #pragma unroll
    for (int i = 0; i < 2; ++i) {
      int g = i * 256 + tid;           // 0..511 segs; row g>>5, slot g&31
      union { ushort4 u4; __hip_bfloat16 h[4]; } p;
      p.h[0] = __float2bfloat16(raw[i].x);
      p.h[1] = __float2bfloat16(raw[i].y);
      p.h[2] = __float2bfloat16(raw[i].z);
      p.h[3] = __float2bfloat16(raw[i].w);
      int row = g >> 5, o8 = g & 31;
      *reinterpret_cast<ushort4*>(
          XsB + row * 256 + ((o8 * 8) ^ ((row & 7) << 4))) = p.u4;
    }

    // ---- issue next tile's contiguous loads (in flight across compute). --
    const int tn = t + stride;
    if (tn < T16) {
      const float* xt = x + (long)tn * 2048;
      #pragma unroll
      for (int i = 0; i < 2; ++i)
        raw[i] = *reinterpret_cast<const float4*>(xt + (i * 256 + tid) * 4);
    }

    // B1: x-stage visible to all waves (LDS only; vmcnt stays pending).
    asm volatile("s_waitcnt lgkmcnt(0)" ::: "memory");
    __builtin_amdgcn_sched_barrier(0);
    __builtin_amdgcn_s_barrier();

    // ---- fragments + MFMA. wave w owns nt = 2w, 2w+1 (out cols 32w..). --
    bf16x8 af[4];
    #pragma unroll
    for (int s = 0; s < 4; ++s)
      af[s] = *reinterpret_cast<const bf16x8*>(
          XsB + m * 256 + ((s * 64 + q * 16) ^ ((m & 7) << 4)));

    f32x4 acc[2];
    acc[0] = (f32x4){0.f, 0.f, 0.f, 0.f};
    acc[1] = (f32x4){0.f, 0.f, 0.f, 0.f};
    #pragma unroll
    for (int s = 0; s < 4; ++s) {
      #pragma unroll
      for (int k = 0; k < 2; ++k) {
        const int nt = 2 * wave + k;
        bf16x8 wfrag = *reinterpret_cast<const bf16x8*>(
            WsB + (nt * 16 + m) * 256 + ((s * 64 + q * 16) ^ ((m & 7) << 4)));
        acc[k] = __builtin_amdgcn_mfma_f32_16x16x32_bf16(wfrag, af[s],
                                                         acc[k], 0, 0, 0);
      }
    }

    // B2: all waves done reading XsB -> reusable as f32 scratch.
    __builtin_amdgcn_s_barrier();

    // ---- scratch write: D(reg j, lane) -> row m, col (2w+k)*16+q*4+j. ----
    #pragma unroll
    for (int k = 0; k < 2; ++k)
      *reinterpret_cast<f32x4*>(
          XsB + m * 512 +
          (((2 * wave + k) * 64 + q * 16) ^ ((m & 7) << 4))) = acc[k];

    // B3: scratch visible.
    asm volatile("s_waitcnt lgkmcnt(0)" ::: "memory");
    __builtin_amdgcn_sched_barrier(0);
    __builtin_amdgcn_s_barrier();

    // ---- coalesced store: 2 x 4KB-contiguous instrs/thread. ----
    {
      char* ob = (char*)out + (long)t * 8192;
      #pragma unroll
      for (int i = 0; i < 2; ++i) {
        int g = i * 256 + tid;         // row g>>5, f32x4 slot g&31
        f32x4 v = *reinterpret_cast<const f32x4*>(
            XsB + (g >> 5) * 512 + (((g & 31) * 16) ^ (((g >> 5) & 7) << 4)));
        *reinterpret_cast<f32x4*>(ob + g * 16) = v;
      }
    }

    // B4: scratch reads done -> next iteration may repack XsB.
    __builtin_amdgcn_s_barrier();

    if (tn >= T16) break;
    t = tn;
  }
}

__device__ __forceinline__ int detect_i64(const int* eidx) {
  int or_odd = 0;
  #pragma unroll
  for (int k = 0; k < 16; ++k) or_odd |= eidx[2 * k + 1];
  return or_odd == 0;   // int64 little-endian: high words all zero
}

// Phase A: one block per edge. Read h rows from `out` (pure read), compute
// attn, write contribution vector 0.1*attn*h_src to ws. No races.
__global__ __launch_bounds__(128) void gat_edge_attn(
    const int* __restrict__ eidx,
    const float* __restrict__ a,       // [4, 64]
    const float* __restrict__ h,       // == out, post-GEMM
    float* __restrict__ contrib,       // [E, 128] in ws
    int E) {
  const int e = blockIdx.x;
  const int c = threadIdx.x;
  const bool is64 = detect_i64(eidx);
  const int src = is64 ? eidx[2 * e] : eidx[e];
  const int dst = is64 ? eidx[2 * (E + e)] : eidx[E + e];

  const float hs = h[(long)src * 128 + c];
  const float hd = h[(long)dst * 128 + c];

  const int head = c >> 5, d = c & 31;
  float term = a[head * 64 + d] * hs + a[head * 64 + 32 + d] * hd;
  // reduce over the 32 lanes of this head (heads occupy 32-lane halves)
  term += __shfl_xor(term, 16);
  term += __shfl_xor(term, 8);
  term += __shfl_xor(term, 4);
  term += __shfl_xor(term, 2);
  term += __shfl_xor(term, 1);
  const float attn = term >= 0.f ? term : 0.2f * term;   // leaky_relu(0.2)

  contrib[(long)e * 128 + c] = 0.1f * attn * hs;
}

// Phase B: atomic scatter-add of contributions (duplicate dst handled by HW).
__global__ __launch_bounds__(128) void gat_edge_scatter(
    const int* __restrict__ eidx,
    const float* __restrict__ contrib,
    float* __restrict__ out,
    int E) {
  const int e = blockIdx.x;
  const int c = threadIdx.x;
  const bool is64 = detect_i64(eidx);
  const int dst = is64 ? eidx[2 * (E + e)] : eidx[E + e];
  atomicAdd(&out[(long)dst * 128 + c], contrib[(long)e * 128 + c]);
}

extern "C" void kernel_launch(void* const* d_in, const int* in_sizes, int n_in,
                              void* d_out, int out_size, void* d_ws, size_t ws_size,
                              hipStream_t stream) {
  const float* x  = (const float*)d_in[0];
  const int* eidx = (const int*)d_in[1];
  const float* W  = (const float*)d_in[2];
  const float* a  = (const float*)d_in[3];
  float* out = (float*)d_out;
  float* contrib = (float*)d_ws;     // needs E*128*4 = 256 KB

  const int N = in_sizes[0] / 128;   // 200000
  const int E = in_sizes[1] / 2;     // 500

  // 1024 blocks = 4 blocks/CU (LDS 40960 = 160K/4, VGPR <= 128) -> 16 w/CU.
  int blocks = 1024;
  gat_gemm_kernel<<<blocks, 256, 0, stream>>>(x, W, out, N);
  gat_edge_attn<<<E, 128, 0, stream>>>(eidx, a, out, contrib, E);
  gat_edge_scatter<<<E, 128, 0, stream>>>(eidx, contrib, out, E);
}